// Round 2
// baseline (625.906 us; speedup 1.0000x reference)
//
#include <hip/hip_runtime.h>

typedef unsigned short u16;
typedef unsigned int u32;

#define N_NODES 20000
#define NE 320000
#define NLAYERS 4
#define NCLASS 40
#define NEG_SLOPE 0.2f
#define LSTRIDE ((NLAYERS + 1) * 128)  // 640 floats per node in X_all/Y_all

typedef __bf16 bf16x8 __attribute__((ext_vector_type(8)));
typedef float f32x4 __attribute__((ext_vector_type(4)));

__device__ inline u16 f2bf(float f) {
    u32 u = __float_as_uint(f);
    return (u16)((u + 0x7fffu + ((u >> 16) & 1u)) >> 16);  // round-nearest-even
}
__device__ inline float bf2f(u16 u) { return __uint_as_float(((u32)u) << 16); }

// ---------------- init: Xbf=bf16(x), X_all[:,0,:]=x, Y_all[:,0,:]=x ----------------
__global__ void k_init(const float* __restrict__ x, u16* __restrict__ Xbf,
                       float* __restrict__ Xall, float* __restrict__ Yall) {
    int t = blockIdx.x * 256 + threadIdx.x;
    if (t >= N_NODES * 128) return;
    float v = x[t];
    Xbf[t] = f2bf(v);
    int n = t >> 7, c = t & 127;
    int ob = n * LSTRIDE + c;  // layer-0 slot
    Xall[ob] = v;
    Yall[ob] = v;
}

// ---------------- Wt[512][128] = bf16(W^T) ----------------
__global__ void k_trans(const float* __restrict__ W, u16* __restrict__ Wt) {
    int t = blockIdx.x * 256 + threadIdx.x;  // 65536 threads
    int k = t >> 9, col = t & 511;
    Wt[col * 128 + k] = f2bf(W[t]);
}

// ---------------- fold attention vectors through W: Vs/Vd[128][4] (f32, exact path) ----------------
__global__ void k_fold(const float* __restrict__ W, const float* __restrict__ att_s,
                       const float* __restrict__ att_d, float* __restrict__ Vs,
                       float* __restrict__ Vd) {
    int t = threadIdx.x;  // 128 threads, 1 block; t = input-channel row of W
    for (int hd = 0; hd < 4; hd++) {
        float s1 = 0.f, s2 = 0.f;
        for (int c = 0; c < 128; c++) {
            float w = W[t * 512 + hd * 128 + c];
            s1 += w * att_s[hd * 128 + c];
            s2 += w * att_d[hd * 128 + c];
        }
        Vs[t * 4 + hd] = s1;
        Vd[t * 4 + hd] = s2;
    }
}

// ---------------- CSR build over dst (self loops included) ----------------
__global__ void k_ones(int* __restrict__ counts) {
    int t = blockIdx.x * 256 + threadIdx.x;
    if (t < N_NODES) counts[t] = 1;  // self loop
}
__global__ void k_count(const int* __restrict__ dst, int* __restrict__ counts) {
    int t = blockIdx.x * 256 + threadIdx.x;
    if (t < NE) atomicAdd(&counts[dst[t]], 1);
}
__global__ void k_scan(const int* __restrict__ counts, int* __restrict__ indptr,
                       int* __restrict__ cursor) {
    __shared__ int part[1024];
    int t = threadIdx.x;
    const int CH = 20;  // 1024*20 >= 20000
    int c0 = t * CH;
    int s = 0;
    for (int i = 0; i < CH; i++) {
        int idx = c0 + i;
        if (idx < N_NODES) s += counts[idx];
    }
    part[t] = s;
    __syncthreads();
    for (int off = 1; off < 1024; off <<= 1) {
        int v = 0;
        if (t >= off) v = part[t - off];
        __syncthreads();
        if (t >= off) part[t] += v;
        __syncthreads();
    }
    int ex = (t == 0) ? 0 : part[t - 1];
    for (int i = 0; i < CH; i++) {
        int idx = c0 + i;
        if (idx < N_NODES) {
            indptr[idx] = ex;
            cursor[idx] = ex;
            ex += counts[idx];
        }
    }
    if (t == 1023) indptr[N_NODES] = part[1023];
}
__global__ void k_scatter(const int* __restrict__ src, const int* __restrict__ dst,
                          int* __restrict__ cursor, int* __restrict__ esrc) {
    int t = blockIdx.x * 256 + threadIdx.x;
    if (t >= NE + N_NODES) return;
    int s, d;
    if (t < NE) { s = src[t]; d = dst[t]; }
    else { s = d = t - NE; }
    int pos = atomicAdd(&cursor[d], 1);
    esrc[pos] = s;
}

// ---------------- GEMM: hbf[N][512] = bf16(Xbf[N][128] @ W[128][512]), MFMA ----------------
__global__ __launch_bounds__(256) void k_gemm(const u16* __restrict__ Xbf,
                                              const u16* __restrict__ Wt,
                                              u16* __restrict__ hbf) {
    const int r0 = blockIdx.x * 64;
    const int c0 = blockIdx.y * 64;
    __shared__ u16 As[64 * 136];  // +8 pad breaks 256B-stride bank aliasing
    __shared__ u16 Bs[64 * 136];
    const int t = threadIdx.x;
    for (int i = 0; i < 4; i++) {
        int flat = i * 256 + t;  // 1024 chunks of 8 u16
        int row = flat >> 4;
        int kc = flat & 15;
        uint4 av = make_uint4(0u, 0u, 0u, 0u);
        int gr = r0 + row;
        if (gr < N_NODES) av = *(const uint4*)(Xbf + gr * 128 + kc * 8);
        *(uint4*)(As + row * 136 + kc * 8) = av;
        uint4 bv = *(const uint4*)(Wt + (c0 + row) * 128 + kc * 8);
        *(uint4*)(Bs + row * 136 + kc * 8) = bv;
    }
    __syncthreads();
    const int wave = t >> 6, lane = t & 63;
    const int wr = (wave >> 1) * 32, wc = (wave & 1) * 32;
    const int lrow = lane & 15, quad = lane >> 4;
    f32x4 acc[2][2] = {};
    for (int kk = 0; kk < 128; kk += 32) {
        bf16x8 a[2], b[2];
        for (int mi = 0; mi < 2; mi++)
            a[mi] = *(const bf16x8*)(As + (wr + mi * 16 + lrow) * 136 + kk + quad * 8);
        for (int ni = 0; ni < 2; ni++)
            b[ni] = *(const bf16x8*)(Bs + (wc + ni * 16 + lrow) * 136 + kk + quad * 8);
        for (int mi = 0; mi < 2; mi++)
            for (int ni = 0; ni < 2; ni++)
                acc[mi][ni] = __builtin_amdgcn_mfma_f32_16x16x32_bf16(a[mi], b[ni], acc[mi][ni], 0, 0, 0);
    }
    for (int mi = 0; mi < 2; mi++)
        for (int ni = 0; ni < 2; ni++)
            for (int r = 0; r < 4; r++) {
                int row = r0 + wr + mi * 16 + quad * 4 + r;
                int col = c0 + wc + ni * 16 + lrow;
                if (row < N_NODES) hbf[row * 512 + col] = f2bf(acc[mi][ni][r]);
            }
}

// ---------------- attention logits: a_s/a_d[N][4] = X @ Vs/Vd (one wave per node) ----------------
__global__ __launch_bounds__(256) void k_att(const float* __restrict__ Xall, int layer,
                                             const float* __restrict__ Vs,
                                             const float* __restrict__ Vd,
                                             float* __restrict__ a_s, float* __restrict__ a_d) {
    int wid = (blockIdx.x * 256 + threadIdx.x) >> 6;  // node, grid exact
    int lane = threadIdx.x & 63;
    const float* Xr = Xall + wid * LSTRIDE + layer * 128;
    float x0 = Xr[lane], x1 = Xr[64 + lane];
    f32x4 vs0 = *(const f32x4*)(Vs + lane * 4), vs1 = *(const f32x4*)(Vs + (64 + lane) * 4);
    f32x4 vd0 = *(const f32x4*)(Vd + lane * 4), vd1 = *(const f32x4*)(Vd + (64 + lane) * 4);
    f32x4 ps = x0 * vs0 + x1 * vs1;
    f32x4 pd = x0 * vd0 + x1 * vd1;
    for (int off = 32; off; off >>= 1)
        for (int c = 0; c < 4; c++) {
            ps[c] += __shfl_xor(ps[c], off);
            pd[c] += __shfl_xor(pd[c], off);
        }
    if (lane == 0) {
        *(f32x4*)(a_s + wid * 4) = ps;
        *(f32x4*)(a_d + wid * 4) = pd;
    }
}

// ---------------- fused per-dst-node: softmax max/den + weighted aggregate + epilogue ----------------
__global__ __launch_bounds__(256) void k_aggr(
    const int* __restrict__ indptr, const int* __restrict__ esrc,
    const float* __restrict__ a_s, const float* __restrict__ a_d,
    const u16* __restrict__ hbf, const float* __restrict__ bias,
    u16* __restrict__ Xbf, float* __restrict__ Xall, float* __restrict__ Yall, int layer) {
    int d = (blockIdx.x * 256 + threadIdx.x) >> 6;  // grid exact: 5000 blocks -> 20000 waves
    int lane = threadIdx.x & 63;
    int start = indptr[d], end = indptr[d + 1];
    f32x4 ad = *(const f32x4*)(a_d + d * 4);
    // pass 1: per-head max of leaky_relu(a_s[s]+a_d[d])
    f32x4 mx = {-1e30f, -1e30f, -1e30f, -1e30f};
    for (int j = start + lane; j < end; j += 64) {
        int s = esrc[j];
        f32x4 e = *(const f32x4*)(a_s + s * 4) + ad;
        for (int c = 0; c < 4; c++) {
            float v = e[c];
            v = v > 0.f ? v : NEG_SLOPE * v;
            mx[c] = fmaxf(mx[c], v);
        }
    }
    for (int off = 32; off; off >>= 1)
        for (int c = 0; c < 4; c++) mx[c] = fmaxf(mx[c], __shfl_xor(mx[c], off));
    // pass 2: denominator (self-loop guarantees den >= 1)
    f32x4 den = {0.f, 0.f, 0.f, 0.f};
    for (int j = start + lane; j < end; j += 64) {
        int s = esrc[j];
        f32x4 e = *(const f32x4*)(a_s + s * 4) + ad;
        for (int c = 0; c < 4; c++) {
            float v = e[c];
            v = v > 0.f ? v : NEG_SLOPE * v;
            den[c] += __expf(v - mx[c]);
        }
    }
    for (int off = 32; off; off >>= 1)
        for (int c = 0; c < 4; c++) den[c] += __shfl_xor(den[c], off);
    // pass 3: aggregate 512 channels; lane owns channels [lane*8, lane*8+8) -> head = lane>>4
    int hd = lane >> 4;
    float mxh = mx[hd], rden = 1.f / den[hd], adh = ad[hd];
    float acc[8] = {0.f, 0.f, 0.f, 0.f, 0.f, 0.f, 0.f, 0.f};
    for (int j = start; j < end; j++) {
        int s = esrc[j];
        float e = a_s[s * 4 + hd] + adh;
        e = e > 0.f ? e : NEG_SLOPE * e;
        float alpha = __expf(e - mxh) * rden;
        uint4 hv = *(const uint4*)(hbf + s * 512 + lane * 8);
        u32 hu[4] = {hv.x, hv.y, hv.z, hv.w};
        for (int q = 0; q < 4; q++) {
            acc[q * 2] += alpha * __uint_as_float(hu[q] << 16);
            acc[q * 2 + 1] += alpha * __uint_as_float(hu[q] & 0xffff0000u);
        }
    }
    // epilogue: +bias, elu, mean-of-4-consecutive (head-major -> out chan), recurrence
    f32x4 b0 = *(const f32x4*)(bias + lane * 8);
    f32x4 b1 = *(const f32x4*)(bias + lane * 8 + 4);
    float g[8];
    for (int i = 0; i < 4; i++) g[i] = acc[i] + b0[i];
    for (int i = 0; i < 4; i++) g[4 + i] = acc[4 + i] + b1[i];
    for (int i = 0; i < 8; i++) {
        float v = g[i];
        g[i] = v > 0.f ? v : __expf(v) - 1.f;
    }
    float agg0 = (g[0] + g[1] + g[2] + g[3]) * 0.25f;  // out channel lane*2
    float agg1 = (g[4] + g[5] + g[6] + g[7]) * 0.25f;  // out channel lane*2+1
    int i0 = lane * 2;
    int xo = d * LSTRIDE + layer * 128 + i0;
    int no = d * LSTRIDE + (layer + 1) * 128 + i0;
    float x0 = Xall[xo], x1 = Xall[xo + 1];
    Xall[no] = agg0;          // X2 = agg
    Xall[no + 1] = agg1;
    Yall[no] = agg0 - x0;     // Y2 = agg - X_prev
    Yall[no + 1] = agg1 - x1;
    Xbf[d * 128 + i0] = f2bf(agg0);
    Xbf[d * 128 + i0 + 1] = f2bf(agg1);
}

// ---------------- readout: out[N][40] = X_final @ Wr^T + br ----------------
__global__ __launch_bounds__(256) void k_out(const float* __restrict__ Xall,
                                             const float* __restrict__ Wr,
                                             const float* __restrict__ br,
                                             float* __restrict__ out) {
    __shared__ float Xs[4][128];
    int wave = threadIdx.x >> 6, lane = threadIdx.x & 63;
    int n = blockIdx.x * 4 + wave;  // grid exact: 5000 blocks
    const float* Xr = Xall + n * LSTRIDE + NLAYERS * 128;
    Xs[wave][lane] = Xr[lane];
    Xs[wave][64 + lane] = Xr[64 + lane];
    __syncthreads();
    if (lane < NCLASS) {
        float acc = 0.f;
        for (int kc = 0; kc < 32; kc++) {
            f32x4 wv = *(const f32x4*)(Wr + lane * 128 + kc * 4);
            for (int q = 0; q < 4; q++) acc += Xs[wave][kc * 4 + q] * wv[q];
        }
        out[n * NCLASS + lane] = acc + br[lane];
    }
}

extern "C" void kernel_launch(void* const* d_in, const int* in_sizes, int n_in,
                              void* d_out, int out_size, void* d_ws, size_t ws_size,
                              hipStream_t stream) {
    const float* x = (const float*)d_in[0];
    const int* src = (const int*)d_in[1];
    const int* dst = (const int*)d_in[2];
    const float* W = (const float*)d_in[3];
    const float* att_s = (const float*)d_in[4];
    const float* att_d = (const float*)d_in[5];
    const float* bias = (const float*)d_in[6];
    const float* Wr = (const float*)d_in[7];
    const float* br = (const float*)d_in[8];

    float* out = (float*)d_out;
    float* Xall = out + (size_t)N_NODES * NCLASS;
    float* Yall = Xall + (size_t)N_NODES * LSTRIDE;

    char* p = (char*)d_ws;
    auto alloc = [&](size_t bytes) -> char* {
        char* r = p;
        p += (bytes + 255) & ~(size_t)255;
        return r;
    };
    u16* Xbf = (u16*)alloc((size_t)N_NODES * 128 * 2);
    u16* hbf = (u16*)alloc((size_t)N_NODES * 512 * 2);
    u16* Wt = (u16*)alloc(512 * 128 * 2);
    float* a_s = (float*)alloc((size_t)N_NODES * 4 * 4);
    float* a_d = (float*)alloc((size_t)N_NODES * 4 * 4);
    float* Vs = (float*)alloc(128 * 4 * 4);
    float* Vd = (float*)alloc(128 * 4 * 4);
    int* indptr = (int*)alloc((N_NODES + 1) * 4);
    int* cursor = (int*)alloc(N_NODES * 4);
    int* counts = (int*)alloc(N_NODES * 4);
    int* esrc = (int*)alloc((size_t)(NE + N_NODES) * 4);

    k_init<<<(N_NODES * 128 + 255) / 256, 256, 0, stream>>>(x, Xbf, Xall, Yall);
    k_trans<<<(512 * 128) / 256, 256, 0, stream>>>(W, Wt);
    k_fold<<<1, 128, 0, stream>>>(W, att_s, att_d, Vs, Vd);
    k_ones<<<(N_NODES + 255) / 256, 256, 0, stream>>>(counts);
    k_count<<<(NE + 255) / 256, 256, 0, stream>>>(dst, counts);
    k_scan<<<1, 1024, 0, stream>>>(counts, indptr, cursor);
    k_scatter<<<(NE + N_NODES + 255) / 256, 256, 0, stream>>>(src, dst, cursor, esrc);

    for (int layer = 0; layer < NLAYERS; layer++) {
        k_gemm<<<dim3((N_NODES + 63) / 64, 8), 256, 0, stream>>>(Xbf, Wt, hbf);
        k_att<<<N_NODES / 4, 256, 0, stream>>>(Xall, layer, Vs, Vd, a_s, a_d);
        k_aggr<<<N_NODES / 4, 256, 0, stream>>>(indptr, esrc, a_s, a_d, hbf, bias,
                                                Xbf, Xall, Yall, layer);
    }
    k_out<<<N_NODES / 4, 256, 0, stream>>>(Xall, Wr, br, out);
}